// Round 9
// baseline (190.848 us; speedup 1.0000x reference)
//
#include <hip/hip_runtime.h>
#include <math.h>

// FFTConvReservoir: y = tanh(ifft(fft(u)*fft(K)).real + D*u); B=8,H=256,L=8192 fp32.
// Round 9: conv LDS halved to 32 KB (one component at a time) -> 3+ blocks/CU.
//  - A<->middle exchanges done component-wise (re then im) through one 8192-float
//    buffer: 6 barriers total (vs 2), but 12+ waves/CU absorb them.
//  - middle transposes (M1<->M2) are wave-private: component-wise through the same
//    buffer with NO barriers (same-wave lgkmcnt ordering; regions disjoint per wave).
//  - all LDS patterns identical to R8's verified 0-conflict set (same SW swizzle).
// Lessons kept: scalar b32 LDS (R7), no launch_bounds occupancy arg (R5), two-kernel
// split (R4), kw=(FFT(K)+D)/N folded in kfft (R6), wave-private middle (R8).

#define LL 8192
#define NT 256
#define HH 256
#define TWO_PI 6.2831853071795864f
#define CP16 0.980785280403230f  // cos(pi/16)
#define SP16 0.195090322016128f  // sin(pi/16)
#define CP8  0.92387953251129f   // cos(pi/8)
#define SP8  0.38268343236509f   // sin(pi/8)

// Bank swizzle: verified 2-way (free) for stride-256, stride-16, contiguous-16.
__device__ __forceinline__ int SW(int e) {
    return e ^ ((e >> 4) & 15) ^ (((e >> 8) & 1) << 4);
}
__device__ __forceinline__ float fast_tanh(float x) {
    float e = __expf(2.0f * x);
    return 1.0f - 2.0f / (e + 1.0f);
}

// Twiddle pyramid: level j at offset (1<<j)-1, length 2^j; top level chained cmul,
// lower levels by squaring.
template<int JT>
__device__ __forceinline__ void fill_pyr_cs(float c0, float s0, float Er, float Ei,
                                            float* twr, float* twi) {
    const int off = (1 << JT) - 1;
    twr[off] = c0; twi[off] = s0;
    #pragma unroll
    for (int m = 1; m < (1 << JT); ++m) {
        const float pr = twr[off + m - 1], pi = twi[off + m - 1];
        twr[off + m] = pr * Er - pi * Ei;
        twi[off + m] = pr * Ei + pi * Er;
    }
    #pragma unroll
    for (int j = JT - 1; j >= 0; --j) {
        #pragma unroll
        for (int m = 0; m < (1 << j); ++m) {
            const float a = twr[(2 << j) - 1 + m], b = twi[(2 << j) - 1 + m];
            twr[(1 << j) - 1 + m] = a * a - b * b;
            twi[(1 << j) - 1 + m] = 2.0f * a * b;
        }
    }
}
template<int JT>
__device__ __forceinline__ void fill_pyr(float ang0, float Er, float Ei,
                                         float* twr, float* twi) {
    float s, c;
    __sincosf(ang0, &s, &c);
    fill_pyr_cs<JT>(c, s, Er, Ei, twr, twi);
}

template<int R2>
__device__ __forceinline__ void dif_apply(float* xr, float* xi,
                                          const float* twr, const float* twi) {
    #pragma unroll
    for (int j = R2 - 1; j >= 0; --j) {
        #pragma unroll
        for (int q = 0; q < (1 << (R2 - 1)); ++q) {
            const int mm = q & ((1 << j) - 1);
            const int m0 = ((q >> j) << (j + 1)) | mm;
            const int m1 = m0 + (1 << j);
            const float wr = twr[(1 << j) - 1 + mm], wi = twi[(1 << j) - 1 + mm];
            const float ar = xr[m0], ai = xi[m0], br = xr[m1], bi = xi[m1];
            xr[m0] = ar + br; xi[m0] = ai + bi;
            const float dr = ar - br, di = ai - bi;
            xr[m1] = dr * wr - di * wi;
            xi[m1] = dr * wi + di * wr;
        }
    }
}
template<int R2>
__device__ __forceinline__ void dit_apply(float* xr, float* xi,
                                          const float* twr, const float* twi) {
    #pragma unroll
    for (int j = 0; j < R2; ++j) {
        #pragma unroll
        for (int q = 0; q < (1 << (R2 - 1)); ++q) {
            const int mm = q & ((1 << j) - 1);
            const int m0 = ((q >> j) << (j + 1)) | mm;
            const int m1 = m0 + (1 << j);
            const float wr = twr[(1 << j) - 1 + mm], wi = twi[(1 << j) - 1 + mm];
            const float br = xr[m1] * wr - xi[m1] * wi;
            const float bi = xr[m1] * wi + xi[m1] * wr;
            const float ar = xr[m0], ai = xi[m0];
            xr[m0] = ar + br; xi[m0] = ai + bi;
            xr[m1] = ar - br; xi[m1] = ai - bi;
        }
    }
}

// ---------------- kfft: unchanged from R8 (verified) ----------------
__device__ __forceinline__ void fwd_A64(float* xr, float* xi, int tid,
                                        float* re, float* im) {
    float twr[31], twi[31];
    fill_pyr<4>(-(TWO_PI / 8192.0f) * (float)tid, CP16, -SP16, twr, twi);
    dif_apply<5>(xr, xi, twr, twi);
    #pragma unroll
    for (int m = 0; m < 32; ++m) {
        const int p = SW(tid + (m << 8));
        re[p] = xr[m]; im[p] = xi[m];
    }
}

__global__ __launch_bounds__(NT) void kfft_kernel(const float* __restrict__ K,
                                                  const float* __restrict__ D,
                                                  float2* __restrict__ Kf) {
    __shared__ float re[LL];
    __shared__ float im[LL];
    const int h = blockIdx.x;
    const int tid = threadIdx.x;
    const float* Kr = K + (size_t)h * LL;
    float xr[32], xi[32];
    #pragma unroll
    for (int m = 0; m < 32; ++m) {
        xr[m] = Kr[tid + (m << 8)];
        xi[m] = 0.0f;
    }
    fwd_A64(xr, xi, tid, re, im);
    __syncthreads();

    const int lane = tid & 63, wv = tid >> 6;
    const int q = lane & 15, qw = (lane >> 4) & 3;

    {   // M1 (stages 7..4)
        float twr[15], twi[15];
        fill_pyr<3>(-(TWO_PI / 256.0f) * (float)q, CP8, -SP8, twr, twi);
        #pragma unroll
        for (int r = 0; r < 2; ++r) {
            const int c = (wv << 3) + qw + (r << 2);
            const int base = (c << 8) + q;
            float ar[16], ai[16];
            #pragma unroll
            for (int m = 0; m < 16; ++m) {
                const int p = SW(base + (m << 4));
                ar[m] = re[p]; ai[m] = im[p];
            }
            dif_apply<4>(ar, ai, twr, twi);
            #pragma unroll
            for (int m = 0; m < 16; ++m) {
                const int p = SW(base + (m << 4));
                re[p] = ar[m]; im[p] = ai[m];
            }
        }
    }
    {   // M2 (stages 3..0) + fold kw = (X + D[h])/N; dwordx4 stores.
        const float dh = D[h];
        const float invN = 1.0f / (float)LL;
        float twr[15], twi[15];
        fill_pyr_cs<3>(1.0f, 0.0f, CP8, -SP8, twr, twi);
        #pragma unroll
        for (int r = 0; r < 2; ++r) {
            const int c = (wv << 3) + qw + (r << 2);
            const int eb = (c << 8) + (q << 4);
            float yr[16], yi[16];
            #pragma unroll
            for (int j = 0; j < 16; ++j) {
                const int p = SW(eb + j);
                yr[j] = re[p]; yi[j] = im[p];
            }
            dif_apply<4>(yr, yi, twr, twi);
            float4* o4 = (float4*)(Kf + (size_t)h * LL + eb);
            #pragma unroll
            for (int jj = 0; jj < 8; ++jj) {
                float4 v;
                v.x = (yr[2 * jj]     + dh) * invN; v.y = yi[2 * jj]     * invN;
                v.z = (yr[2 * jj + 1] + dh) * invN; v.w = yi[2 * jj + 1] * invN;
                o4[jj] = v;
            }
        }
    }
}

// ---------------- conv: 32 KB LDS, component-wise exchanges ----------------
__global__ __launch_bounds__(NT) void conv_kernel(const float* __restrict__ u,
                                                  const float2* __restrict__ Kf,
                                                  float* __restrict__ out) {
    __shared__ float buf[LL];   // 32 KB — one component at a time
    const int tid = threadIdx.x;
    const int h = blockIdx.x & (HH - 1);
    const int pr_ = blockIdx.x >> 8;        // batch pair 0..3
    const size_t off0 = ((size_t)(pr_ * 2) * HH + h) * LL;
    const size_t off1 = off0 + (size_t)HH * LL;
    const float* u0 = u + off0;
    const float* u1 = u + off1;

    float xr[32], xi[32];
    #pragma unroll
    for (int m = 0; m < 32; ++m) {
        xr[m] = u0[tid + (m << 8)];
        xi[m] = u1[tid + (m << 8)];
    }
    {   // pass A (stages 12..8) in-register
        float twr[31], twi[31];
        fill_pyr<4>(-(TWO_PI / 8192.0f) * (float)tid, CP16, -SP16, twr, twi);
        dif_apply<5>(xr, xi, twr, twi);
    }
    const int lane = tid & 63, wv = tid >> 6;
    const int q = lane & 15, qw = (lane >> 4) & 3;
    const int c0 = (wv << 3) + qw;          // round-0 chunk; round-1 = c0+4

    // ---- A-exchange, component-wise (3 barriers) ----
    #pragma unroll
    for (int m = 0; m < 32; ++m) buf[SW(tid + (m << 8))] = xr[m];
    __syncthreads();
    float ar[2][16], ai[2][16];
    #pragma unroll
    for (int r = 0; r < 2; ++r) {
        #pragma unroll
        for (int m = 0; m < 16; ++m)
            ar[r][m] = buf[SW(((c0 + (r << 2)) << 8) + q + (m << 4))];
    }
    __syncthreads();
    #pragma unroll
    for (int m = 0; m < 32; ++m) buf[SW(tid + (m << 8))] = xi[m];
    __syncthreads();
    #pragma unroll
    for (int r = 0; r < 2; ++r) {
        #pragma unroll
        for (int m = 0; m < 16; ++m)
            ai[r][m] = buf[SW(((c0 + (r << 2)) << 8) + q + (m << 4))];
    }

    // ---- wave-private middle: no barriers (disjoint per-wave chunk regions) ----
    const float2* kf = Kf + (size_t)h * LL;
    #pragma unroll
    for (int r = 0; r < 2; ++r) {
        const int cb = (c0 + (r << 2)) << 8;
        // kw load issued early — latency overlaps M1 + transpose
        float kwr[16], kwi[16];
        {
            const float4* kp = (const float4*)(kf + cb + (q << 4));
            #pragma unroll
            for (int jj = 0; jj < 8; ++jj) {
                const float4 v = kp[jj];
                kwr[2 * jj] = v.x;     kwi[2 * jj] = v.y;
                kwr[2 * jj + 1] = v.z; kwi[2 * jj + 1] = v.w;
            }
        }
        {   // M1: stages 7..4 in-register
            float t1r[15], t1i[15];
            fill_pyr<3>(-(TWO_PI / 256.0f) * (float)q, CP8, -SP8, t1r, t1i);
            dif_apply<4>(ar[r], ai[r], t1r, t1i);
        }
        // transpose M1->M2 layout, component-wise, wave-private (no barrier)
        float yr[16], yi[16];
        #pragma unroll
        for (int m = 0; m < 16; ++m) buf[SW(cb + q + (m << 4))] = ar[r][m];
        #pragma unroll
        for (int j = 0; j < 16; ++j) yr[j] = buf[SW(cb + (q << 4) + j)];
        #pragma unroll
        for (int m = 0; m < 16; ++m) buf[SW(cb + q + (m << 4))] = ai[r][m];
        #pragma unroll
        for (int j = 0; j < 16; ++j) yi[j] = buf[SW(cb + (q << 4) + j)];
        {   // M2: stages 3..0, *kw, inverse stages 0..3
            float tdr[15], tdi[15];
            fill_pyr_cs<3>(1.0f, 0.0f, CP8, -SP8, tdr, tdi);
            dif_apply<4>(yr, yi, tdr, tdi);
            #pragma unroll
            for (int j = 0; j < 16; ++j) {
                const float a = yr[j], b = yi[j];
                yr[j] = a * kwr[j] - b * kwi[j];
                yi[j] = a * kwi[j] + b * kwr[j];
            }
            float tur[15], tui[15];
            fill_pyr_cs<3>(1.0f, 0.0f, CP8, SP8, tur, tui);
            dit_apply<4>(yr, yi, tur, tui);
        }
        // transpose back M2->M1 layout (no barrier)
        #pragma unroll
        for (int j = 0; j < 16; ++j) buf[SW(cb + (q << 4) + j)] = yr[j];
        #pragma unroll
        for (int m = 0; m < 16; ++m) ar[r][m] = buf[SW(cb + q + (m << 4))];
        #pragma unroll
        for (int j = 0; j < 16; ++j) buf[SW(cb + (q << 4) + j)] = yi[j];
        #pragma unroll
        for (int m = 0; m < 16; ++m) ai[r][m] = buf[SW(cb + q + (m << 4))];
        {   // M1': inverse stages 4..7
            float t1r[15], t1i[15];
            fill_pyr<3>((TWO_PI / 256.0f) * (float)q, CP8, SP8, t1r, t1i);
            dit_apply<4>(ar[r], ai[r], t1r, t1i);
        }
    }

    // ---- A'-exchange, component-wise (3 barriers) ----
    // own-region writes need no preceding barrier (other waves only touch their own
    // regions until the cross-region reads below, which are barrier-protected).
    #pragma unroll
    for (int r = 0; r < 2; ++r) {
        #pragma unroll
        for (int m = 0; m < 16; ++m)
            buf[SW(((c0 + (r << 2)) << 8) + q + (m << 4))] = ar[r][m];
    }
    __syncthreads();
    #pragma unroll
    for (int m = 0; m < 32; ++m) xr[m] = buf[SW(tid + (m << 8))];
    __syncthreads();
    #pragma unroll
    for (int r = 0; r < 2; ++r) {
        #pragma unroll
        for (int m = 0; m < 16; ++m)
            buf[SW(((c0 + (r << 2)) << 8) + q + (m << 4))] = ai[r][m];
    }
    __syncthreads();
    #pragma unroll
    for (int m = 0; m < 32; ++m) xi[m] = buf[SW(tid + (m << 8))];

    {   // pass A' (stages 8..12) in-register
        float twr[31], twi[31];
        fill_pyr<4>((TWO_PI / 8192.0f) * (float)tid, CP16, SP16, twr, twi);
        dit_apply<5>(xr, xi, twr, twi);
    }
    float* o0 = out + off0;
    float* o1 = out + off1;
    #pragma unroll
    for (int m = 0; m < 32; ++m) {
        const int n = tid + (m << 8);
        o0[n] = fast_tanh(xr[m]);
        o1[n] = fast_tanh(xi[m]);
    }
}

extern "C" void kernel_launch(void* const* d_in, const int* in_sizes, int n_in,
                              void* d_out, int out_size, void* d_ws, size_t ws_size,
                              hipStream_t stream) {
    const float* u = (const float*)d_in[0];   // (8, 256, 8192)
    const float* K = (const float*)d_in[1];   // (256, 8192)
    const float* D = (const float*)d_in[2];   // (256,)
    float* out = (float*)d_out;               // (8, 256, 8192)
    float2* Kf = (float2*)d_ws;               // 256 * 8192 float2 = 16 MB

    kfft_kernel<<<dim3(HH), dim3(NT), 0, stream>>>(K, D, Kf);
    conv_kernel<<<dim3(4 * HH), dim3(NT), 0, stream>>>(u, Kf, out);
}